// Round 5
// baseline (62943.427 us; speedup 1.0000x reference)
//
#include <hip/hip_runtime.h>

#define NPTS 288
#define DIMS 2048
#define KC   6
#define N_IT 25
#define BLK  1024
#define NSL  4              // dim-slices per batch (1 block each)
#define SLD  (DIMS / NSL)   // 512 dims per slice
#define TD   64             // dims per tile
#define NT   (SLD / TD)     // 8 tiles per slice
#define TP   66             // tile row stride in words ([j][d] layout)

// ---------------- K0: init centers = first KC points ----------------
__global__ __launch_bounds__(BLK) void k_init(const float* __restrict__ x,
                                              float* __restrict__ cent) {
  const int b = blockIdx.x >> 2, s = blockIdx.x & 3;
  const int t = threadIdx.x;
  const float* __restrict__ Mb = x + (size_t)b * (DIMS * NPTS);
#pragma unroll
  for (int i = 0; i < 3; ++i) {
    const int e  = t + BLK * i;      // 0..3071 = KC*SLD
    const int k  = e >> 9;
    const int cl = e & (SLD - 1);
    const int c  = s * SLD + cl;
    cent[((size_t)b * KC + k) * DIMS + c] = Mb[(size_t)c * NPTS + k];
  }
}

// ---------------- K1: dots for the INITIAL centers (prologue only) ----------------
__global__ __launch_bounds__(BLK) void k_dots(const float* __restrict__ x,
                                              const float* __restrict__ cent,
                                              float* __restrict__ part,
                                              float* __restrict__ csqp) {
  const int b = blockIdx.x >> 2, s = blockIdx.x & 3;
  const int t = threadIdx.x, wv = t >> 6, lane = t & 63;
  const float* __restrict__ Mb = x + (size_t)b * (DIMS * NPTS);
  const float* __restrict__ cb = cent + (size_t)b * (KC * DIMS);

  __shared__ __attribute__((aligned(16))) float cs[KC][SLD];
  __shared__ float part_l[3][KC][NPTS];
#pragma unroll
  for (int i = 0; i < 3; ++i) {
    const int e = t + BLK * i;
    const int k = e >> 9, cl = e & (SLD - 1);
    cs[k][cl] = cb[(size_t)k * DIMS + s * SLD + cl];
  }
  __syncthreads();

  if (wv < 15) {
    const int g = wv / 5;
    const int q = t - g * 320;
    if (q < NPTS) {
      const int c0 = (g == 0) ? 0   : (g == 1 ? 172 : 344);
      const int c1 = (g == 0) ? 172 : (g == 1 ? 344 : 512);
      float acc[KC];
#pragma unroll
      for (int k = 0; k < KC; ++k) acc[k] = 0.f;
      const float* __restrict__ pb = Mb + (size_t)(s * SLD) * NPTS + q;
#pragma unroll 2
      for (int c = c0; c < c1; c += 4) {
        const float p0 = pb[(size_t)(c + 0) * NPTS];
        const float p1 = pb[(size_t)(c + 1) * NPTS];
        const float p2 = pb[(size_t)(c + 2) * NPTS];
        const float p3 = pb[(size_t)(c + 3) * NPTS];
#pragma unroll
        for (int k = 0; k < KC; ++k) {
          const float4 cv = *(const float4*)&cs[k][c];
          acc[k] += p0 * cv.x + p1 * cv.y + p2 * cv.z + p3 * cv.w;
        }
      }
#pragma unroll
      for (int k = 0; k < KC; ++k) part_l[g][k][q] = acc[k];
    }
  } else {
    float a[KC];
#pragma unroll
    for (int k = 0; k < KC; ++k) a[k] = 0.f;
#pragma unroll
    for (int i = 0; i < SLD / 64; ++i) {
#pragma unroll
      for (int k = 0; k < KC; ++k) {
        const float v = cs[k][lane + 64 * i];
        a[k] += v * v;
      }
    }
#pragma unroll
    for (int k = 0; k < KC; ++k) {
#pragma unroll
      for (int off = 32; off; off >>= 1) a[k] += __shfl_xor(a[k], off, 64);
    }
    if (lane == 0) {
#pragma unroll
      for (int k = 0; k < KC; ++k)
        csqp[(size_t)(b * NSL + s) * KC + k] = a[k];
    }
  }
  __syncthreads();

  if (t < NPTS) {
#pragma unroll
    for (int k = 0; k < KC; ++k)
      part[((size_t)(b * NSL + s) * KC + k) * NPTS + t] =
          part_l[0][k][t] + part_l[1][k][t] + part_l[2][k][t];
  }
}

// ---------------- K2: fully-fused iteration, ONE sweep of x ----------------
// per 64-dim tile: stage (prefetched) -> sums(old assign) -> update cs -> dots partial
__global__ __launch_bounds__(BLK) void k_iter(const float* __restrict__ x,
                                              float* __restrict__ cent,
                                              float* __restrict__ part,
                                              float* __restrict__ csqp,
                                              int do_dots) {
  const int b = blockIdx.x >> 2, s = blockIdx.x & 3;
  const int t = threadIdx.x, wv = t >> 6, lane = t & 63;
  const float* __restrict__ Mb = x + (size_t)b * (DIMS * NPTS);
  float* __restrict__ cb = cent + (size_t)b * (KC * DIMS);

  __shared__ __attribute__((aligned(16))) float cs[KC][SLD];   // 12,288 B
  __shared__ float tile[NPTS * TP];                            // 76,032 B  [j][d] stride 66
  __shared__ float pool[KC][TD][17];                           // 26,112 B  (exchange buf after loop)
  __shared__ __attribute__((aligned(16))) int assign_s[NPTS];  // 1,152 B
  __shared__ float csqh[KC];
  __shared__ int cnt_i[KC];

  float* exbuf = &pool[0][0][0];   // [NPTS][KC] after tile loop

  // ---- issue prefetch of tile 0 immediately (hides under argmin phase) ----
  float pre[18];
  {
    const float* __restrict__ src = Mb + (size_t)(s * SLD) * NPTS;   // dt = 0, linear
#pragma unroll
    for (int i = 0; i < 18; ++i) pre[i] = src[t + BLK * i];
  }

  // old centers slice -> LDS
#pragma unroll
  for (int i = 0; i < 3; ++i) {
    const int e = t + BLK * i;
    const int k = e >> 9, cl = e & (SLD - 1);
    cs[k][cl] = cb[(size_t)k * DIMS + s * SLD + cl];
  }

  // ---- argmin phase (redundant per slice-block; fixed order = deterministic) ----
  if (t < KC) {
    const float* pc = csqp + (size_t)b * NSL * KC + t;
    csqh[t] = 0.5f * (pc[0] + pc[KC] + pc[2 * KC] + pc[3 * KC]);
    cnt_i[t] = 0;
  }
  __syncthreads();

  int myA = -1;
  if (t < NPTS) {
    const float* pp = part + (size_t)b * NSL * KC * NPTS + t;
    float best = 0.f;
    int bi = 0;
#pragma unroll
    for (int k = 0; k < KC; ++k) {
      const float S = pp[(size_t)k * NPTS] + pp[(size_t)(KC + k) * NPTS] +
                      pp[(size_t)(2 * KC + k) * NPTS] + pp[(size_t)(3 * KC + k) * NPTS];
      const float sc = csqh[k] - S;     // argmin_k(d) == argmin_k(csq/2 - S)
      if (k == 0 || sc < best) { best = sc; bi = k; }
    }
    assign_s[t] = bi;
    myA = bi;
  }
  if (t < 320) {   // waves 0..4, uniform per-wave predicate
#pragma unroll
    for (int k = 0; k < KC; ++k) {
      unsigned long long m = __ballot(myA == k);
      if (lane == 0) atomicAdd(&cnt_i[k], (int)__popcll(m));
    }
  }
  __syncthreads();   // assign + counts ready

  // hoist this wave's 18 point-assignments into SGPRs
  int aj[18];
#pragma unroll
  for (int r = 0; r < 18; ++r)
    aj[r] = __builtin_amdgcn_readfirstlane(assign_s[wv * 18 + r]);

  // dots state: waves 0-4 <-> points x dims[0,32); waves 5-9 <-> points x dims[32,64)
  const int grp  = wv / 5;                 // 0,1 active; 2,3 idle in dots
  const int dq   = t - grp * 320;          // point index for grp<2
  const bool dact = (wv < 10) && (dq < NPTS);
  float acc[KC];
#pragma unroll
  for (int k = 0; k < KC; ++k) acc[k] = 0.f;

  // ---- tile loop: ONE pass over x ----
  for (int dt = 0; dt < NT; ++dt) {
    __syncthreads();                       // (A) tile free (prev dots done reading)
#pragma unroll
    for (int i = 0; i < 18; ++i) {         // regs -> tile  [j][d] stride 66
      const int e = t + BLK * i;
      const int d = e / NPTS, j = e - d * NPTS;
      tile[j * TP + d] = pre[i];
    }
    __syncthreads();                       // (B) tile ready

    if (dt + 1 < NT) {                     // issue next-tile loads (hide under compute)
      const float* __restrict__ src = Mb + (size_t)(s * SLD + (dt + 1) * TD) * NPTS;
#pragma unroll
      for (int i = 0; i < 18; ++i) pre[i] = src[t + BLK * i];
    }

    // sums: lane <-> dim, wave <-> 18 points; scalar branch on SGPR assignment
    {
      float s0 = 0, s1 = 0, s2 = 0, s3 = 0, s4 = 0, s5 = 0;
      const int jb = wv * 18;
#pragma unroll
      for (int r = 0; r < 18; ++r) {
        const float p = tile[(jb + r) * TP + lane];
        const int a = aj[r];
        if      (a == 0) s0 += p;
        else if (a == 1) s1 += p;
        else if (a == 2) s2 += p;
        else if (a == 3) s3 += p;
        else if (a == 4) s4 += p;
        else             s5 += p;
      }
      pool[0][lane][wv] = s0; pool[1][lane][wv] = s1; pool[2][lane][wv] = s2;
      pool[3][lane][wv] = s3; pool[4][lane][wv] = s4; pool[5][lane][wv] = s5;
    }
    __syncthreads();                       // (C) pool ready

    if (t < KC * TD) {                     // 384 threads: reduce 16 waves, update cs
      const int k = t >> 6, d = t & 63;
      float sum = 0.f;
#pragma unroll
      for (int w = 0; w < 16; ++w) sum += pool[k][d][w];   // fixed order
      const int cn = cnt_i[k];
      const int cl = dt * TD + d;
      cs[k][cl] = (cn > 0) ? (sum / (float)cn) : cs[k][cl];
    }
    __syncthreads();                       // (D) new cs for this tile ready

    // dots partial for these 64 dims from the SAME tile (new centers)
    if (do_dots && dact) {
      const int base = dq * TP + grp * 32;
      const int cbase = dt * TD + grp * 32;
#pragma unroll
      for (int db = 0; db < 8; ++db) {
        const float2 p01 = *(const float2*)&tile[base + db * 4];
        const float2 p23 = *(const float2*)&tile[base + db * 4 + 2];
#pragma unroll
        for (int k = 0; k < KC; ++k) {
          const float4 cv = *(const float4*)&cs[k][cbase + db * 4];  // uniform broadcast
          acc[k] += p01.x * cv.x + p01.y * cv.y + p23.x * cv.z + p23.y * cv.w;
        }
      }
    }
  }

  // store new centers (next dispatch + final output read them)
#pragma unroll
  for (int i = 0; i < 3; ++i) {
    const int e = t + BLK * i;
    const int k = e >> 9, cl = e & (SLD - 1);
    cb[(size_t)k * DIMS + s * SLD + cl] = cs[k][cl];
  }

  if (do_dots) {
    __syncthreads();                       // dots done; pool area free for exchange
    if (wv >= 5 && wv < 10 && dq < NPTS) {
#pragma unroll
      for (int k = 0; k < KC; ++k) exbuf[dq * KC + k] = acc[k];
    }
    if (wv == 15) {
      // csq of the NEW centers
      float a[KC];
#pragma unroll
      for (int k = 0; k < KC; ++k) a[k] = 0.f;
#pragma unroll
      for (int i = 0; i < SLD / 64; ++i) {
#pragma unroll
        for (int k = 0; k < KC; ++k) {
          const float v = cs[k][lane + 64 * i];
          a[k] += v * v;
        }
      }
#pragma unroll
      for (int k = 0; k < KC; ++k) {
#pragma unroll
        for (int off = 32; off; off >>= 1) a[k] += __shfl_xor(a[k], off, 64);
      }
      if (lane == 0) {
#pragma unroll
        for (int k = 0; k < KC; ++k)
          csqp[(size_t)(b * NSL + s) * KC + k] = a[k];
      }
    }
    __syncthreads();                       // exbuf ready
    if (t < NPTS) {
      float* __restrict__ pp = part + (size_t)(b * NSL + s) * KC * NPTS + t;
#pragma unroll
      for (int k = 0; k < KC; ++k)
        pp[(size_t)k * NPTS] = acc[k] + exbuf[t * KC + k];   // dims[0,32)+dims[32,64) halves
    }
  }
}

// ---------------- K3a/K3b: transpose [KC][DIMS] -> [DIMS][KC] via ws staging ----------------
__global__ __launch_bounds__(BLK) void k_stage(const float* __restrict__ cent,
                                               float* __restrict__ stage) {
  const int b = blockIdx.x >> 2, s = blockIdx.x & 3;
  const int t = threadIdx.x;
#pragma unroll
  for (int i = 0; i < 3; ++i) {
    const int e = t + BLK * i;
    const int k = e >> 9, cl = e & (SLD - 1);
    stage[(size_t)blockIdx.x * 3072 + e] =
        cent[((size_t)b * KC + k) * DIMS + s * SLD + cl];
  }
}

__global__ __launch_bounds__(BLK) void k_out(const float* __restrict__ stage,
                                             float* __restrict__ out) {
  const int b = blockIdx.x >> 2, s = blockIdx.x & 3;
  const int t = threadIdx.x;
#pragma unroll
  for (int i = 0; i < 3; ++i) {
    const int e  = t + BLK * i;
    const int cl = e / KC;
    const int k  = e - cl * KC;
    const int c  = s * SLD + cl;
    out[((size_t)b * DIMS + c) * KC + k] =
        stage[(size_t)blockIdx.x * 3072 + k * SLD + cl];
  }
}

extern "C" void kernel_launch(void* const* d_in, const int* in_sizes, int n_in,
                              void* d_out, int out_size, void* d_ws, size_t ws_size,
                              hipStream_t stream) {
  const float* x = (const float*)d_in[0];
  float* out     = (float*)d_out;
  const int nb   = in_sizes[0] / (DIMS * NPTS);   // 64

  float* cent  = out;                                       // centers live in d_out
  float* part  = (float*)d_ws;                              // nb*NSL*KC*NPTS floats
  float* csqp  = part + (size_t)nb * NSL * KC * NPTS;
  float* stage = part;                                      // reuse after last k_iter

  const dim3 grid(nb * NSL), blk(BLK);
  hipLaunchKernelGGL(k_init, grid, blk, 0, stream, x, cent);
  hipLaunchKernelGGL(k_dots, grid, blk, 0, stream, x, cent, part, csqp);
  for (int it = 0; it < N_IT; ++it) {
    hipLaunchKernelGGL(k_iter, grid, blk, 0, stream, x, cent, part, csqp,
                       (it < N_IT - 1) ? 1 : 0);
  }
  hipLaunchKernelGGL(k_stage, grid, blk, 0, stream, cent, stage);
  hipLaunchKernelGGL(k_out,   grid, blk, 0, stream, stage, out);
}